// Round 11
// baseline (267.053 us; speedup 1.0000x reference)
//
#include <hip/hip_runtime.h>
#include <hip/hip_bf16.h>
#include <hip/hip_fp16.h>
#include <float.h>

// GAT, 3 layers: (8,8,concat) -> relu -> (8,8,concat) -> relu -> (4,1,mean)
// N=50000, E=800000 (+N self-loops).
// R10 -> R11: XCD-pinned feature-split gather.
//   gather64's floor was 8 XCDs x 6.4MB = 51MB compulsory xwh traffic.
//   Split each node's gather into two feature-half blocks and steer halves
//   to disjoint XCD sets via blockIdx (dispatch round-robins bid%8 across
//   XCDs; mapping affects locality only, not correctness):
//     bid&3 -> node-quad low bits, (bid>>2)&1 -> feature half.
//   Each XCD then touches only 3.2MB of xwh (fits 4MB XCD-L2) -> compulsory
//   25.6MB and random reads become L2 hits.
//   Cost: layer-3 fusion reverted (half-blocks can't form the full row):
//   gemm_att4 (~4us) + hfeat write return. pk3/ai3 packing kept for gather4.
// CSR build, fp16 xwh, no-max softmax unchanged from R10.

#define FDIM 64
#define BSHIFT 7                 // 128 nodes per bucket
#define BNODES (1 << BSHIFT)
#define BINCH 8192               // edges per binscatter block

__device__ __forceinline__ int clampN(int v, int N) {
  return ((unsigned)v >= (unsigned)N) ? 0 : v;
}

// zero bucketCount; block 0 detects edge_index word stride
// (int64 upload => odd 32-bit words all zero since ids < 2^31).
__global__ __launch_bounds__(256) void init_kernel(
    const int* __restrict__ ei, int E, int* __restrict__ bucketCount, int NB,
    int* __restrict__ flag) {
  int i = blockIdx.x * 256 + threadIdx.x;
  if (i < NB) bucketCount[i] = 0;
  if (blockIdx.x == 0) {
    __shared__ int any;
    if (threadIdx.x == 0) any = 0;
    __syncthreads();
    int idx = 2 * threadIdx.x + 1;
    int v = (idx < 2 * E) ? ei[idx] : 0;
    if (v != 0) atomicOr(&any, 1);
    __syncthreads();
    if (threadIdx.x == 0) *flag = any ? 1 : 2;
  }
}

// coarse histogram of dst buckets (LDS-accumulated, few global atomics)
__global__ __launch_bounds__(256) void hist_kernel(
    const int* __restrict__ ei, const int* __restrict__ flag, int E, int N,
    int NB, int* __restrict__ bucketCount) {
  __shared__ int hist[512];
  int st = *flag;
  for (int i = threadIdx.x; i < NB; i += 256) hist[i] = 0;
  __syncthreads();
  int ET = E + N;
  for (int e = blockIdx.x * 256 + threadIdx.x; e < ET; e += gridDim.x * 256) {
    int dst = (e < E) ? clampN(ei[(size_t)st * (E + e)], N) : (e - E);
    atomicAdd(&hist[dst >> BSHIFT], 1);
  }
  __syncthreads();
  for (int i = threadIdx.x; i < NB; i += 256)
    if (hist[i]) atomicAdd(&bucketCount[i], hist[i]);
}

// 1-block scan of NB (<=512) bucket counts -> bucketBase (excl), fill=base
__global__ __launch_bounds__(512) void bucket_scan_kernel(
    const int* __restrict__ bucketCount, int NB, int* __restrict__ bucketBase,
    int* __restrict__ bucketFill, int* __restrict__ rowstart, int N, int ET) {
  __shared__ int s[512];
  int t = threadIdx.x;
  int v = (t < NB) ? bucketCount[t] : 0;
  s[t] = v;
  __syncthreads();
  for (int off = 1; off < 512; off <<= 1) {
    int x = (t >= off) ? s[t - off] : 0;
    __syncthreads();
    s[t] += x;
    __syncthreads();
  }
  if (t < NB) {
    int excl = s[t] - v;
    bucketBase[t] = excl;
    bucketFill[t] = excl;
  }
  if (t == 0) {
    bucketBase[NB] = s[511];  // == ET
    rowstart[N] = ET;
  }
}

// each block owns BINCH contiguous edges: LDS hist -> per-bucket global
// reservation -> write packed (src<<7|localdst) into per-bucket streams
__global__ __launch_bounds__(256) void binscatter_kernel(
    const int* __restrict__ ei, const int* __restrict__ flag, int E, int N,
    int NB, int* __restrict__ bucketFill, unsigned* __restrict__ pairbuf,
    int ET) {
  __shared__ int hist[512];
  __shared__ int cursor[512];
  int st = *flag;
  int e0 = blockIdx.x * BINCH;
  int e1 = min(e0 + BINCH, ET);
  for (int i = threadIdx.x; i < NB; i += 256) hist[i] = 0;
  __syncthreads();
  for (int e = e0 + threadIdx.x; e < e1; e += 256) {
    int dst = (e < E) ? clampN(ei[(size_t)st * (E + e)], N) : (e - E);
    atomicAdd(&hist[dst >> BSHIFT], 1);
  }
  __syncthreads();
  for (int i = threadIdx.x; i < NB; i += 256)
    cursor[i] = hist[i] ? atomicAdd(&bucketFill[i], hist[i]) : 0;
  __syncthreads();
  for (int e = e0 + threadIdx.x; e < e1; e += 256) {
    int src, dst;
    if (e < E) {
      src = clampN(ei[(size_t)st * e], N);
      dst = clampN(ei[(size_t)st * (E + e)], N);
    } else {
      src = e - E; dst = e - E;
    }
    int pos = atomicAdd(&cursor[dst >> BSHIFT], 1);
    if ((unsigned)pos < (unsigned)ET)
      pairbuf[pos] = ((unsigned)src << BSHIFT) | (unsigned)(dst & (BNODES - 1));
  }
}

// one block per bucket: local degree count -> LDS scan -> rowstart; then
// cursor-scatter col within the bucket's contiguous edge range (L2-local)
__global__ __launch_bounds__(256) void bucketbuild_kernel(
    const unsigned* __restrict__ pairbuf, const int* __restrict__ bucketBase,
    int N, int ET, int* __restrict__ rowstart, int* __restrict__ col) {
  __shared__ int s[BNODES];
  int b = blockIdx.x;
  int t = threadIdx.x;
  int base = bucketBase[b], end = bucketBase[b + 1];
  int n0 = b << BSHIFT;
  int nn = min(BNODES, N - n0);
  if (t < BNODES) s[t] = 0;
  __syncthreads();
  for (int e = base + t; e < end; e += 256) {
    int li = pairbuf[e] & (BNODES - 1);
    atomicAdd(&s[li], 1);
  }
  __syncthreads();
  int myd = (t < BNODES) ? s[t] : 0;
  for (int off = 1; off < BNODES; off <<= 1) {
    int v = (t >= off && t < BNODES) ? s[t - off] : 0;
    __syncthreads();
    if (t < BNODES) s[t] += v;
    __syncthreads();
  }
  int excl = (t < BNODES) ? (s[t] - myd) : 0;
  if (t < nn) rowstart[n0 + t] = base + excl;
  __syncthreads();
  if (t < BNODES) s[t] = excl;  // cursors
  __syncthreads();
  for (int e = base + t; e < end; e += 256) {
    unsigned p = pairbuf[e];
    int li = p & (BNODES - 1);
    int pos = base + atomicAdd(&s[li], 1);
    if ((unsigned)pos < (unsigned)ET) col[pos] = (int)(p >> BSHIFT);
  }
}

// Layers 1-2 projection: xwh(fp16) = x@W (64x64) + fp32 scores.
// Block = 256 threads; tile = 64 nodes; thread computes a 4x4 output block.
__global__ __launch_bounds__(256) void gemm_att64_kernel(
    const float* __restrict__ x, const float* __restrict__ W,
    const float* __restrict__ att, int N, __half* __restrict__ xwh,
    float* __restrict__ ai, float* __restrict__ aj) {
  __shared__ float Wl[64 * 64];
  __shared__ float xqT[64 * 68];  // [k][n], stride 68: 272B rows (16B aligned)
  int tid = threadIdx.x;
  for (int i = tid; i < 64 * 64; i += 256) Wl[i] = W[i];
  int jq = tid & 15, nq = tid >> 4;
  float aI[4], aJ[4];
  #pragma unroll
  for (int ji = 0; ji < 4; ++ji) {
    int j = jq * 4 + ji, h = j >> 3, c = j & 7;
    aI[ji] = att[h * 16 + c];
    aJ[ji] = att[h * 16 + 8 + c];
  }
  int ntiles = (N + 63) >> 6;
  for (int tile = blockIdx.x; tile < ntiles; tile += gridDim.x) {
    int n0 = tile << 6;
    __syncthreads();  // protect xqT reuse
    for (int idx = tid; idx < 4096; idx += 256) {
      int n = idx >> 6, k = idx & 63;   // per wave: k = lane (coalesced)
      int gn = n0 + n;
      xqT[k * 68 + n] = (gn < N) ? x[(size_t)gn * 64 + k] : 0.f;
    }
    __syncthreads();
    float acc[4][4];
    #pragma unroll
    for (int i = 0; i < 4; ++i)
      #pragma unroll
      for (int j = 0; j < 4; ++j) acc[i][j] = 0.f;
    #pragma unroll 8
    for (int k = 0; k < 64; ++k) {
      float4 xv = *(const float4*)&xqT[k * 68 + nq * 4];
      float4 wv = *(const float4*)&Wl[k * 64 + jq * 4];
      acc[0][0] += xv.x * wv.x; acc[0][1] += xv.x * wv.y;
      acc[0][2] += xv.x * wv.z; acc[0][3] += xv.x * wv.w;
      acc[1][0] += xv.y * wv.x; acc[1][1] += xv.y * wv.y;
      acc[1][2] += xv.y * wv.z; acc[1][3] += xv.y * wv.w;
      acc[2][0] += xv.z * wv.x; acc[2][1] += xv.z * wv.y;
      acc[2][2] += xv.z * wv.z; acc[2][3] += xv.z * wv.w;
      acc[3][0] += xv.w * wv.x; acc[3][1] += xv.w * wv.y;
      acc[3][2] += xv.w * wv.z; acc[3][3] += xv.w * wv.w;
    }
    #pragma unroll
    for (int ni = 0; ni < 4; ++ni) {
      int gn = n0 + nq * 4 + ni;
      float pi = acc[ni][0] * aI[0] + acc[ni][1] * aI[1] +
                 acc[ni][2] * aI[2] + acc[ni][3] * aI[3];
      float pj = acc[ni][0] * aJ[0] + acc[ni][1] * aJ[1] +
                 acc[ni][2] * aJ[2] + acc[ni][3] * aJ[3];
      // jq and jq^1 cover the same head (j=4jq..4jq+3 => h=jq>>1)
      pi += __shfl_xor(pi, 1, 16);
      pj += __shfl_xor(pj, 1, 16);
      if (gn < N) {
        __half2 pk[2];
        pk[0] = __floats2half2_rn(acc[ni][0], acc[ni][1]);
        pk[1] = __floats2half2_rn(acc[ni][2], acc[ni][3]);
        *(uint2*)&xwh[(size_t)gn * 64 + jq * 4] = *(uint2*)pk;
        if (!(jq & 1)) {
          int h = jq >> 1;
          ai[gn * 8 + h] = pi;
          aj[gn * 8 + h] = pj;
        }
      }
    }
  }
}

// Layer 3 projection from hfeat: packed (xw3,aj3) pairs + ai3.
__global__ __launch_bounds__(256) void gemm_att4_kernel(
    const float* __restrict__ x, const float* __restrict__ W,
    const float* __restrict__ att, int N, float* __restrict__ pk3,
    float* __restrict__ ai3) {
  int t = blockIdx.x * 256 + threadIdx.x;
  int n = t >> 2;
  if (n >= N) return;
  int j = t & 3;
  const float* xr = x + (size_t)n * 64;
  float acc = 0.f;
  #pragma unroll
  for (int k = 0; k < 64; ++k) acc += xr[k] * W[k * 4 + j];
  pk3[(size_t)n * 8 + j * 2]     = acc;                 // xw3
  pk3[(size_t)n * 8 + j * 2 + 1] = acc * att[j * 2 + 1];  // aj3
  ai3[(size_t)n * 4 + j]         = acc * att[j * 2];      // ai3
}

// Layers 1-2 aggregation, XCD-pinned feature-split:
//   bid&3 -> node-quad low bits, (bid>>2)&1 -> feature half (steers halves
//   to XCD sets {0-3} / {4-7} under round-robin bid%8 dispatch).
// Block = 4 nodes x 1 wave; wave = 8 edge-slots x 8 lanes; lane holds 4
// features (8B fp16x4). 2 edges per slot in flight (16/wave). relu fused.
__global__ __launch_bounds__(256) void gather64_kernel(
    const __half* __restrict__ xwh, const float* __restrict__ ai,
    const float* __restrict__ aj, const int* __restrict__ rowstart,
    const int* __restrict__ col, const float* __restrict__ bias, int N,
    float* __restrict__ out) {
  int bid = blockIdx.x;
  int half = (bid >> 2) & 1;
  int quad = (bid >> 3) * 4 + (bid & 3);
  int n = quad * 4 + (threadIdx.x >> 6);
  if (n >= N) return;
  int lane = threadIdx.x & 63;
  int slot = lane >> 3;            // 0..7: edge slot
  int li = lane & 7;               // feature quad within half
  int f4 = half * 32 + li * 4;
  int h = f4 >> 3;
  int r0 = rowstart[n], r1 = rowstart[n + 1];
  float ain = ai[n * 8 + h];
  float dn = 0.f;
  float4 acc = make_float4(0.f, 0.f, 0.f, 0.f);
  int e = r0 + slot;
  for (; e + 8 < r1; e += 16) {    // 2 edges per slot in flight
    int sA = clampN(col[e],     N);
    int sB = clampN(col[e + 8], N);
    float aA = aj[sA * 8 + h], aB = aj[sB * 8 + h];
    uint2 rA = *(const uint2*)&xwh[(size_t)sA * 64 + f4];
    uint2 rB = *(const uint2*)&xwh[(size_t)sB * 64 + f4];
    float eA = ain + aA; eA = (eA > 0.f) ? eA : 0.2f * eA;
    float eB = ain + aB; eB = (eB > 0.f) ? eB : 0.2f * eB;
    float pA = __expf(eA), pB = __expf(eB);
    dn += pA + pB;
    float2 A0 = __half22float2(*(__half2*)&rA.x), A1 = __half22float2(*(__half2*)&rA.y);
    float2 B0 = __half22float2(*(__half2*)&rB.x), B1 = __half22float2(*(__half2*)&rB.y);
    acc.x += pA * A0.x + pB * B0.x;
    acc.y += pA * A0.y + pB * B0.y;
    acc.z += pA * A1.x + pB * B1.x;
    acc.w += pA * A1.y + pB * B1.y;
  }
  if (e < r1) {
    int s = clampN(col[e], N);
    float a = aj[s * 8 + h];
    uint2 r = *(const uint2*)&xwh[(size_t)s * 64 + f4];
    float ev = ain + a; ev = (ev > 0.f) ? ev : 0.2f * ev;
    float p = __expf(ev);
    dn += p;
    float2 v0 = __half22float2(*(__half2*)&r.x);
    float2 v1 = __half22float2(*(__half2*)&r.y);
    acc.x += p * v0.x; acc.y += p * v0.y;
    acc.z += p * v1.x; acc.w += p * v1.y;
  }
  // reduce the 8 slots (lane bits 3,4,5)
  dn += __shfl_xor(dn, 8); dn += __shfl_xor(dn, 16); dn += __shfl_xor(dn, 32);
  acc.x += __shfl_xor(acc.x, 8); acc.x += __shfl_xor(acc.x, 16); acc.x += __shfl_xor(acc.x, 32);
  acc.y += __shfl_xor(acc.y, 8); acc.y += __shfl_xor(acc.y, 16); acc.y += __shfl_xor(acc.y, 32);
  acc.z += __shfl_xor(acc.z, 8); acc.z += __shfl_xor(acc.z, 16); acc.z += __shfl_xor(acc.z, 32);
  acc.w += __shfl_xor(acc.w, 8); acc.w += __shfl_xor(acc.w, 16); acc.w += __shfl_xor(acc.w, 32);
  if (slot == 0) {
    float4 bv = *(const float4*)&bias[f4];
    float inv = 1.f / dn;
    float4 o = make_float4(fmaxf(acc.x * inv + bv.x, 0.f),
                           fmaxf(acc.y * inv + bv.y, 0.f),
                           fmaxf(acc.z * inv + bv.z, 0.f),
                           fmaxf(acc.w * inv + bv.w, 0.f));  // relu fused
    *(float4*)&out[(size_t)n * 64 + f4] = o;
  }
}

// Layer 3 aggregation + head-mean + bias. 4 lanes per node, one 8B
// (xw3,aj3) load per edge per lane. No max-shift.
__global__ __launch_bounds__(256) void gather4_kernel(
    const float* __restrict__ pk3, const float* __restrict__ ai3,
    const int* __restrict__ rowstart, const int* __restrict__ col,
    const float* __restrict__ b3, int N, float* __restrict__ out) {
  int t = blockIdx.x * 256 + threadIdx.x;
  int n = t >> 2;
  if (n >= N) return;
  int h = t & 3;
  int r0 = rowstart[n], r1 = rowstart[n + 1];
  float ain = ai3[n * 4 + h];
  float denom = 0.f, acc = 0.f;
  int e = r0;
  for (; e + 4 <= r1; e += 4) {
    int s0 = clampN(col[e + 0], N);
    int s1 = clampN(col[e + 1], N);
    int s2 = clampN(col[e + 2], N);
    int s3 = clampN(col[e + 3], N);
    float2 v0 = *(const float2*)&pk3[(size_t)s0 * 8 + h * 2];
    float2 v1 = *(const float2*)&pk3[(size_t)s1 * 8 + h * 2];
    float2 v2 = *(const float2*)&pk3[(size_t)s2 * 8 + h * 2];
    float2 v3 = *(const float2*)&pk3[(size_t)s3 * 8 + h * 2];
    float e0 = ain + v0.y; e0 = (e0 > 0.f) ? e0 : 0.2f * e0;
    float e1 = ain + v1.y; e1 = (e1 > 0.f) ? e1 : 0.2f * e1;
    float e2 = ain + v2.y; e2 = (e2 > 0.f) ? e2 : 0.2f * e2;
    float e3 = ain + v3.y; e3 = (e3 > 0.f) ? e3 : 0.2f * e3;
    float p0 = __expf(e0), p1 = __expf(e1);
    float p2 = __expf(e2), p3 = __expf(e3);
    denom += (p0 + p1) + (p2 + p3);
    acc += p0 * v0.x; acc += p1 * v1.x; acc += p2 * v2.x; acc += p3 * v3.x;
  }
  for (; e < r1; ++e) {
    int s = clampN(col[e], N);
    float2 v = *(const float2*)&pk3[(size_t)s * 8 + h * 2];
    float ev = ain + v.y;
    ev = (ev > 0.f) ? ev : 0.2f * ev;
    float p = __expf(ev);
    denom += p;
    acc += p * v.x;
  }
  float o = acc / denom;
  o += __shfl_xor(o, 1, 4);
  o += __shfl_xor(o, 2, 4);
  o *= 0.25f;
  if (h == 0) out[n] = o + b3[0];
}

extern "C" void kernel_launch(void* const* d_in, const int* in_sizes, int n_in,
                              void* d_out, int out_size, void* d_ws, size_t ws_size,
                              hipStream_t stream) {
  const float* X    = (const float*)d_in[0];
  const int*   ei   = (const int*)d_in[1];
  const float* W1   = (const float*)d_in[2];
  const float* att1 = (const float*)d_in[3];
  const float* b1   = (const float*)d_in[4];
  const float* W2   = (const float*)d_in[5];
  const float* att2 = (const float*)d_in[6];
  const float* b2   = (const float*)d_in[7];
  const float* W3   = (const float*)d_in[8];
  const float* att3 = (const float*)d_in[9];
  const float* b3   = (const float*)d_in[10];
  float* out = (float*)d_out;

  const int N  = in_sizes[0] / FDIM;   // 50000
  const int E  = in_sizes[1] / 2;      // 800000
  const int ET = E + N;
  const int NB = (N + BNODES - 1) >> BSHIFT;  // 391 buckets (<=512)

  char* ws = (char*)d_ws;
  auto carve = [&](size_t bytes) {
    char* p = ws; ws += (bytes + 15) & ~(size_t)15; return p;
  };
  __half*   xwh       = (__half*)carve((size_t)N * 64 * 2);  // fp16 rows
  float*    hfeat     = (float*)carve((size_t)N * 64 * 4);
  float*    pk3       = (float*)carve((size_t)N * 8 * 4);   // (xw3,aj3) pairs
  float*    ai3       = (float*)carve((size_t)N * 4 * 4);
  float*    ai        = (float*)carve((size_t)N * 8 * 4);
  float*    aj        = (float*)carve((size_t)N * 8 * 4);
  int*      rowstart  = (int*)carve((size_t)(N + 1) * 4);
  int*      colidx    = (int*)carve((size_t)ET * 4);
  int*      stflag    = (int*)carve(16);
  int*      bucketCnt = (int*)carve(512 * 4);
  int*      bucketBas = (int*)carve(513 * 4);
  int*      bucketFil = (int*)carve(512 * 4);
  size_t need = (size_t)(ws - (char*)d_ws);
  if (ws_size < need) return;
  // pairbuf aliases hfeat (12.8MB >= ET*4=3.4MB); CSR build completes before
  // layer-1 gather writes hfeat.
  unsigned* pairbuf = (unsigned*)hfeat;

  // ---- CSR build: bucketed counting sort (once; shared by all 3 layers) ----
  init_kernel<<<(NB + 255) / 256 + 1, 256, 0, stream>>>(ei, E, bucketCnt, NB, stflag);
  hist_kernel<<<128, 256, 0, stream>>>(ei, stflag, E, N, NB, bucketCnt);
  bucket_scan_kernel<<<1, 512, 0, stream>>>(bucketCnt, NB, bucketBas, bucketFil,
                                            rowstart, N, ET);
  binscatter_kernel<<<(ET + BINCH - 1) / BINCH, 256, 0, stream>>>(
      ei, stflag, E, N, NB, bucketFil, pairbuf, ET);
  bucketbuild_kernel<<<NB, 256, 0, stream>>>(pairbuf, bucketBas, N, ET,
                                             rowstart, colidx);

  const int nquads      = (N + 3) / 4;
  const int gatherGrid  = ((nquads + 3) / 4) * 8;  // (quad-group x 4) x (half x 2) interleaved for XCD pinning
  const int laneBlocks4 = (N * 4 + 255) / 256;
  const int gemmTiles   = (N + 63) / 64;

  // ---- layer 1 ----
  gemm_att64_kernel<<<gemmTiles, 256, 0, stream>>>(X, W1, att1, N, xwh, ai, aj);
  gather64_kernel<<<gatherGrid, 256, 0, stream>>>(xwh, ai, aj, rowstart, colidx,
                                                  b1, N, hfeat);
  // ---- layer 2 ----
  gemm_att64_kernel<<<gemmTiles, 256, 0, stream>>>(hfeat, W2, att2, N, xwh, ai, aj);
  gather64_kernel<<<gatherGrid, 256, 0, stream>>>(xwh, ai, aj, rowstart, colidx,
                                                  b2, N, hfeat);
  // ---- layer 3 ----
  gemm_att4_kernel<<<laneBlocks4, 256, 0, stream>>>(hfeat, W3, att3, N, pk3, ai3);
  gather4_kernel<<<laneBlocks4, 256, 0, stream>>>(pk3, ai3, rowstart, colidx,
                                                  b3, N, out);
}

// Round 12
// 243.783 us; speedup vs baseline: 1.0955x; 1.0955x over previous
//
#include <hip/hip_runtime.h>
#include <hip/hip_bf16.h>
#include <hip/hip_fp16.h>
#include <float.h>

// GAT, 3 layers: (8,8,concat) -> relu -> (8,8,concat) -> relu -> (4,1,mean)
// N=50000, E=800000 (+N self-loops).
// R11 -> R12: REVERT to R10 (241us). R11's XCD-pinned feature-split FAILED
// (267us): per-edge overhead (col + full aj row) duplicated across the two
// half-blocks, and bid%8->XCD steering did not pin halves into XCD-L2
// (FETCH 95MB vs predicted 32MB). Both MLP-depth (R8) and XCD-pinning (R11)
// hypotheses for gather64 are now falsified -> it sits at the compulsory
// random-access floor (~51MB per-XCD-cold xwh traffic @ ~2.6TB/s).
// R10 design: bucketed-counting-sort CSR; fused GEMM+scores (fp16 xw);
// no-max-shift softmax (exp shift cancels in ratio, |e|<~10<<88);
// single-pass gather; layer-3 projection fused into layer-2 gather epilogue;
// packed (xw3,aj3) pairs for gather4.

#define FDIM 64
#define BSHIFT 7                 // 128 nodes per bucket
#define BNODES (1 << BSHIFT)
#define BINCH 8192               // edges per binscatter block

__device__ __forceinline__ int clampN(int v, int N) {
  return ((unsigned)v >= (unsigned)N) ? 0 : v;
}

// zero bucketCount; block 0 detects edge_index word stride
// (int64 upload => odd 32-bit words all zero since ids < 2^31).
__global__ __launch_bounds__(256) void init_kernel(
    const int* __restrict__ ei, int E, int* __restrict__ bucketCount, int NB,
    int* __restrict__ flag) {
  int i = blockIdx.x * 256 + threadIdx.x;
  if (i < NB) bucketCount[i] = 0;
  if (blockIdx.x == 0) {
    __shared__ int any;
    if (threadIdx.x == 0) any = 0;
    __syncthreads();
    int idx = 2 * threadIdx.x + 1;
    int v = (idx < 2 * E) ? ei[idx] : 0;
    if (v != 0) atomicOr(&any, 1);
    __syncthreads();
    if (threadIdx.x == 0) *flag = any ? 1 : 2;
  }
}

// coarse histogram of dst buckets (LDS-accumulated, few global atomics)
__global__ __launch_bounds__(256) void hist_kernel(
    const int* __restrict__ ei, const int* __restrict__ flag, int E, int N,
    int NB, int* __restrict__ bucketCount) {
  __shared__ int hist[512];
  int st = *flag;
  for (int i = threadIdx.x; i < NB; i += 256) hist[i] = 0;
  __syncthreads();
  int ET = E + N;
  for (int e = blockIdx.x * 256 + threadIdx.x; e < ET; e += gridDim.x * 256) {
    int dst = (e < E) ? clampN(ei[(size_t)st * (E + e)], N) : (e - E);
    atomicAdd(&hist[dst >> BSHIFT], 1);
  }
  __syncthreads();
  for (int i = threadIdx.x; i < NB; i += 256)
    if (hist[i]) atomicAdd(&bucketCount[i], hist[i]);
}

// 1-block scan of NB (<=512) bucket counts -> bucketBase (excl), fill=base
__global__ __launch_bounds__(512) void bucket_scan_kernel(
    const int* __restrict__ bucketCount, int NB, int* __restrict__ bucketBase,
    int* __restrict__ bucketFill, int* __restrict__ rowstart, int N, int ET) {
  __shared__ int s[512];
  int t = threadIdx.x;
  int v = (t < NB) ? bucketCount[t] : 0;
  s[t] = v;
  __syncthreads();
  for (int off = 1; off < 512; off <<= 1) {
    int x = (t >= off) ? s[t - off] : 0;
    __syncthreads();
    s[t] += x;
    __syncthreads();
  }
  if (t < NB) {
    int excl = s[t] - v;
    bucketBase[t] = excl;
    bucketFill[t] = excl;
  }
  if (t == 0) {
    bucketBase[NB] = s[511];  // == ET
    rowstart[N] = ET;
  }
}

// each block owns BINCH contiguous edges: LDS hist -> per-bucket global
// reservation -> write packed (src<<7|localdst) into per-bucket streams
__global__ __launch_bounds__(256) void binscatter_kernel(
    const int* __restrict__ ei, const int* __restrict__ flag, int E, int N,
    int NB, int* __restrict__ bucketFill, unsigned* __restrict__ pairbuf,
    int ET) {
  __shared__ int hist[512];
  __shared__ int cursor[512];
  int st = *flag;
  int e0 = blockIdx.x * BINCH;
  int e1 = min(e0 + BINCH, ET);
  for (int i = threadIdx.x; i < NB; i += 256) hist[i] = 0;
  __syncthreads();
  for (int e = e0 + threadIdx.x; e < e1; e += 256) {
    int dst = (e < E) ? clampN(ei[(size_t)st * (E + e)], N) : (e - E);
    atomicAdd(&hist[dst >> BSHIFT], 1);
  }
  __syncthreads();
  for (int i = threadIdx.x; i < NB; i += 256)
    cursor[i] = hist[i] ? atomicAdd(&bucketFill[i], hist[i]) : 0;
  __syncthreads();
  for (int e = e0 + threadIdx.x; e < e1; e += 256) {
    int src, dst;
    if (e < E) {
      src = clampN(ei[(size_t)st * e], N);
      dst = clampN(ei[(size_t)st * (E + e)], N);
    } else {
      src = e - E; dst = e - E;
    }
    int pos = atomicAdd(&cursor[dst >> BSHIFT], 1);
    if ((unsigned)pos < (unsigned)ET)
      pairbuf[pos] = ((unsigned)src << BSHIFT) | (unsigned)(dst & (BNODES - 1));
  }
}

// one block per bucket: local degree count -> LDS scan -> rowstart; then
// cursor-scatter col within the bucket's contiguous edge range (L2-local)
__global__ __launch_bounds__(256) void bucketbuild_kernel(
    const unsigned* __restrict__ pairbuf, const int* __restrict__ bucketBase,
    int N, int ET, int* __restrict__ rowstart, int* __restrict__ col) {
  __shared__ int s[BNODES];
  int b = blockIdx.x;
  int t = threadIdx.x;
  int base = bucketBase[b], end = bucketBase[b + 1];
  int n0 = b << BSHIFT;
  int nn = min(BNODES, N - n0);
  if (t < BNODES) s[t] = 0;
  __syncthreads();
  for (int e = base + t; e < end; e += 256) {
    int li = pairbuf[e] & (BNODES - 1);
    atomicAdd(&s[li], 1);
  }
  __syncthreads();
  int myd = (t < BNODES) ? s[t] : 0;
  for (int off = 1; off < BNODES; off <<= 1) {
    int v = (t >= off && t < BNODES) ? s[t - off] : 0;
    __syncthreads();
    if (t < BNODES) s[t] += v;
    __syncthreads();
  }
  int excl = (t < BNODES) ? (s[t] - myd) : 0;
  if (t < nn) rowstart[n0 + t] = base + excl;
  __syncthreads();
  if (t < BNODES) s[t] = excl;  // cursors
  __syncthreads();
  for (int e = base + t; e < end; e += 256) {
    unsigned p = pairbuf[e];
    int li = p & (BNODES - 1);
    int pos = base + atomicAdd(&s[li], 1);
    if ((unsigned)pos < (unsigned)ET) col[pos] = (int)(p >> BSHIFT);
  }
}

// Layers 1-2 projection: xwh(fp16) = x@W (64x64) + fp32 scores.
// Block = 256 threads; tile = 64 nodes; thread computes a 4x4 output block.
__global__ __launch_bounds__(256) void gemm_att64_kernel(
    const float* __restrict__ x, const float* __restrict__ W,
    const float* __restrict__ att, int N, __half* __restrict__ xwh,
    float* __restrict__ ai, float* __restrict__ aj) {
  __shared__ float Wl[64 * 64];
  __shared__ float xqT[64 * 68];  // [k][n], stride 68: 272B rows (16B aligned)
  int tid = threadIdx.x;
  for (int i = tid; i < 64 * 64; i += 256) Wl[i] = W[i];
  int jq = tid & 15, nq = tid >> 4;
  float aI[4], aJ[4];
  #pragma unroll
  for (int ji = 0; ji < 4; ++ji) {
    int j = jq * 4 + ji, h = j >> 3, c = j & 7;
    aI[ji] = att[h * 16 + c];
    aJ[ji] = att[h * 16 + 8 + c];
  }
  int ntiles = (N + 63) >> 6;
  for (int tile = blockIdx.x; tile < ntiles; tile += gridDim.x) {
    int n0 = tile << 6;
    __syncthreads();  // protect xqT reuse
    for (int idx = tid; idx < 4096; idx += 256) {
      int n = idx >> 6, k = idx & 63;   // per wave: k = lane (coalesced)
      int gn = n0 + n;
      xqT[k * 68 + n] = (gn < N) ? x[(size_t)gn * 64 + k] : 0.f;
    }
    __syncthreads();
    float acc[4][4];
    #pragma unroll
    for (int i = 0; i < 4; ++i)
      #pragma unroll
      for (int j = 0; j < 4; ++j) acc[i][j] = 0.f;
    #pragma unroll 8
    for (int k = 0; k < 64; ++k) {
      float4 xv = *(const float4*)&xqT[k * 68 + nq * 4];
      float4 wv = *(const float4*)&Wl[k * 64 + jq * 4];
      acc[0][0] += xv.x * wv.x; acc[0][1] += xv.x * wv.y;
      acc[0][2] += xv.x * wv.z; acc[0][3] += xv.x * wv.w;
      acc[1][0] += xv.y * wv.x; acc[1][1] += xv.y * wv.y;
      acc[1][2] += xv.y * wv.z; acc[1][3] += xv.y * wv.w;
      acc[2][0] += xv.z * wv.x; acc[2][1] += xv.z * wv.y;
      acc[2][2] += xv.z * wv.z; acc[2][3] += xv.z * wv.w;
      acc[3][0] += xv.w * wv.x; acc[3][1] += xv.w * wv.y;
      acc[3][2] += xv.w * wv.z; acc[3][3] += xv.w * wv.w;
    }
    #pragma unroll
    for (int ni = 0; ni < 4; ++ni) {
      int gn = n0 + nq * 4 + ni;
      float pi = acc[ni][0] * aI[0] + acc[ni][1] * aI[1] +
                 acc[ni][2] * aI[2] + acc[ni][3] * aI[3];
      float pj = acc[ni][0] * aJ[0] + acc[ni][1] * aJ[1] +
                 acc[ni][2] * aJ[2] + acc[ni][3] * aJ[3];
      // jq and jq^1 cover the same head (j=4jq..4jq+3 => h=jq>>1)
      pi += __shfl_xor(pi, 1, 16);
      pj += __shfl_xor(pj, 1, 16);
      if (gn < N) {
        __half2 pk[2];
        pk[0] = __floats2half2_rn(acc[ni][0], acc[ni][1]);
        pk[1] = __floats2half2_rn(acc[ni][2], acc[ni][3]);
        *(uint2*)&xwh[(size_t)gn * 64 + jq * 4] = *(uint2*)pk;
        if (!(jq & 1)) {
          int h = jq >> 1;
          ai[gn * 8 + h] = pi;
          aj[gn * 8 + h] = pj;
        }
      }
    }
  }
}

// Layers 1-2 aggregation: block = 4 nodes (1 wave each).
// Wave = 4 edge-slots x 16 lanes; lane holds 4 features as one 8B fp16x4 load.
// No max-shift: exp(e) directly (|e| <~ 10 << 88, shift cancels in ratio).
// fuse3: compute layer-3 projection from the finished row in-register and
// write pk3 (xw3,aj3 interleaved) + ai3 instead of the hfeat row.
__global__ __launch_bounds__(256) void gather64_kernel(
    const __half* __restrict__ xwh, const float* __restrict__ ai,
    const float* __restrict__ aj, const int* __restrict__ rowstart,
    const int* __restrict__ col, const float* __restrict__ bias, int N,
    float* __restrict__ out, int fuse3, const float* __restrict__ W3,
    const float* __restrict__ att3, float* __restrict__ pk3,
    float* __restrict__ ai3) {
  int n = blockIdx.x * 4 + (threadIdx.x >> 6);
  if (n >= N) return;
  int lane = threadIdx.x & 63;
  int slot = lane >> 4;   // which edge in the 4-group
  int li = lane & 15;     // feature quad
  int f4 = li * 4;
  int h = li >> 1;
  int r0 = rowstart[n], r1 = rowstart[n + 1];
  float ain = ai[n * 8 + h];
  float dn = 0.f;
  float4 acc = make_float4(0.f, 0.f, 0.f, 0.f);
  int e = r0 + slot;
  for (; e + 12 < r1; e += 16) {   // 4 edges per slot in flight
    int sA = clampN(col[e],      N);
    int sB = clampN(col[e + 4],  N);
    int sC = clampN(col[e + 8],  N);
    int sD = clampN(col[e + 12], N);
    float aA = aj[sA * 8 + h], aB = aj[sB * 8 + h];
    float aC = aj[sC * 8 + h], aD = aj[sD * 8 + h];
    uint2 rA = *(const uint2*)&xwh[(size_t)sA * 64 + f4];
    uint2 rB = *(const uint2*)&xwh[(size_t)sB * 64 + f4];
    uint2 rC = *(const uint2*)&xwh[(size_t)sC * 64 + f4];
    uint2 rD = *(const uint2*)&xwh[(size_t)sD * 64 + f4];
    float eA = ain + aA; eA = (eA > 0.f) ? eA : 0.2f * eA;
    float eB = ain + aB; eB = (eB > 0.f) ? eB : 0.2f * eB;
    float eC = ain + aC; eC = (eC > 0.f) ? eC : 0.2f * eC;
    float eD = ain + aD; eD = (eD > 0.f) ? eD : 0.2f * eD;
    float pA = __expf(eA), pB = __expf(eB);
    float pC = __expf(eC), pD = __expf(eD);
    dn += (pA + pB) + (pC + pD);
    float2 A0 = __half22float2(*(__half2*)&rA.x), A1 = __half22float2(*(__half2*)&rA.y);
    float2 B0 = __half22float2(*(__half2*)&rB.x), B1 = __half22float2(*(__half2*)&rB.y);
    float2 C0 = __half22float2(*(__half2*)&rC.x), C1 = __half22float2(*(__half2*)&rC.y);
    float2 D0 = __half22float2(*(__half2*)&rD.x), D1 = __half22float2(*(__half2*)&rD.y);
    acc.x += pA * A0.x + pB * B0.x + pC * C0.x + pD * D0.x;
    acc.y += pA * A0.y + pB * B0.y + pC * C0.y + pD * D0.y;
    acc.z += pA * A1.x + pB * B1.x + pC * C1.x + pD * D1.x;
    acc.w += pA * A1.y + pB * B1.y + pC * C1.y + pD * D1.y;
  }
  for (; e < r1; e += 4) {
    int s = clampN(col[e], N);
    float a = aj[s * 8 + h];
    uint2 r = *(const uint2*)&xwh[(size_t)s * 64 + f4];
    float ev = ain + a; ev = (ev > 0.f) ? ev : 0.2f * ev;
    float p = __expf(ev);
    dn += p;
    float2 v0 = __half22float2(*(__half2*)&r.x);
    float2 v1 = __half22float2(*(__half2*)&r.y);
    acc.x += p * v0.x; acc.y += p * v0.y;
    acc.z += p * v1.x; acc.w += p * v1.y;
  }
  // reduce the 4 slots (lane bits 4 and 5) -> all lanes hold full sums
  dn += __shfl_xor(dn, 16); dn += __shfl_xor(dn, 32);
  acc.x += __shfl_xor(acc.x, 16); acc.x += __shfl_xor(acc.x, 32);
  acc.y += __shfl_xor(acc.y, 16); acc.y += __shfl_xor(acc.y, 32);
  acc.z += __shfl_xor(acc.z, 16); acc.z += __shfl_xor(acc.z, 32);
  acc.w += __shfl_xor(acc.w, 16); acc.w += __shfl_xor(acc.w, 32);
  float4 bv = *(const float4*)&bias[f4];
  float inv = 1.f / dn;
  float4 o = make_float4(fmaxf(acc.x * inv + bv.x, 0.f),
                         fmaxf(acc.y * inv + bv.y, 0.f),
                         fmaxf(acc.z * inv + bv.z, 0.f),
                         fmaxf(acc.w * inv + bv.w, 0.f));  // relu fused
  if (!fuse3) {
    if (slot == 0) *(float4*)&out[(size_t)n * 64 + f4] = o;
    return;
  }
  // ---- fused layer-3 projection: pa[j] = sum_f row[f] * W3[f][j] ----
  // o is identical across slots (full reduce above); W3 rows are float4.
  float4 w0 = *(const float4*)&W3[(f4 + 0) * 4];
  float4 w1 = *(const float4*)&W3[(f4 + 1) * 4];
  float4 w2 = *(const float4*)&W3[(f4 + 2) * 4];
  float4 w3 = *(const float4*)&W3[(f4 + 3) * 4];
  float pa0 = o.x * w0.x + o.y * w1.x + o.z * w2.x + o.w * w3.x;
  float pa1 = o.x * w0.y + o.y * w1.y + o.z * w2.y + o.w * w3.y;
  float pa2 = o.x * w0.z + o.y * w1.z + o.z * w2.z + o.w * w3.z;
  float pa3 = o.x * w0.w + o.y * w1.w + o.z * w2.w + o.w * w3.w;
  #pragma unroll
  for (int off = 1; off < 16; off <<= 1) {
    pa0 += __shfl_xor(pa0, off, 16);
    pa1 += __shfl_xor(pa1, off, 16);
    pa2 += __shfl_xor(pa2, off, 16);
    pa3 += __shfl_xor(pa3, off, 16);
  }
  if (lane == 0) {
    // pk3[n][h] = (xw3_h, aj3_h) interleaved; ai3[n][h] separate
    float a0 = att3[0], a1 = att3[1], a2 = att3[2], a3 = att3[3];
    float a4 = att3[4], a5 = att3[5], a6 = att3[6], a7 = att3[7];
    *(float4*)&pk3[(size_t)n * 8 + 0] = make_float4(pa0, pa0 * a1, pa1, pa1 * a3);
    *(float4*)&pk3[(size_t)n * 8 + 4] = make_float4(pa2, pa2 * a5, pa3, pa3 * a7);
    *(float4*)&ai3[(size_t)n * 4] = make_float4(pa0 * a0, pa1 * a2, pa2 * a4, pa3 * a6);
  }
}

// Layer 3 aggregation + head-mean + bias. 4 lanes per node, one 8B
// (xw3,aj3) load per edge per lane. No max-shift.
__global__ __launch_bounds__(256) void gather4_kernel(
    const float* __restrict__ pk3, const float* __restrict__ ai3,
    const int* __restrict__ rowstart, const int* __restrict__ col,
    const float* __restrict__ b3, int N, float* __restrict__ out) {
  int t = blockIdx.x * 256 + threadIdx.x;
  int n = t >> 2;
  if (n >= N) return;
  int h = t & 3;
  int r0 = rowstart[n], r1 = rowstart[n + 1];
  float ain = ai3[n * 4 + h];
  float denom = 0.f, acc = 0.f;
  int e = r0;
  for (; e + 4 <= r1; e += 4) {
    int s0 = clampN(col[e + 0], N);
    int s1 = clampN(col[e + 1], N);
    int s2 = clampN(col[e + 2], N);
    int s3 = clampN(col[e + 3], N);
    float2 v0 = *(const float2*)&pk3[(size_t)s0 * 8 + h * 2];
    float2 v1 = *(const float2*)&pk3[(size_t)s1 * 8 + h * 2];
    float2 v2 = *(const float2*)&pk3[(size_t)s2 * 8 + h * 2];
    float2 v3 = *(const float2*)&pk3[(size_t)s3 * 8 + h * 2];
    float e0 = ain + v0.y; e0 = (e0 > 0.f) ? e0 : 0.2f * e0;
    float e1 = ain + v1.y; e1 = (e1 > 0.f) ? e1 : 0.2f * e1;
    float e2 = ain + v2.y; e2 = (e2 > 0.f) ? e2 : 0.2f * e2;
    float e3 = ain + v3.y; e3 = (e3 > 0.f) ? e3 : 0.2f * e3;
    float p0 = __expf(e0), p1 = __expf(e1);
    float p2 = __expf(e2), p3 = __expf(e3);
    denom += (p0 + p1) + (p2 + p3);
    acc += p0 * v0.x; acc += p1 * v1.x; acc += p2 * v2.x; acc += p3 * v3.x;
  }
  for (; e < r1; ++e) {
    int s = clampN(col[e], N);
    float2 v = *(const float2*)&pk3[(size_t)s * 8 + h * 2];
    float ev = ain + v.y;
    ev = (ev > 0.f) ? ev : 0.2f * ev;
    float p = __expf(ev);
    denom += p;
    acc += p * v.x;
  }
  float o = acc / denom;
  o += __shfl_xor(o, 1, 4);
  o += __shfl_xor(o, 2, 4);
  o *= 0.25f;
  if (h == 0) out[n] = o + b3[0];
}

extern "C" void kernel_launch(void* const* d_in, const int* in_sizes, int n_in,
                              void* d_out, int out_size, void* d_ws, size_t ws_size,
                              hipStream_t stream) {
  const float* X    = (const float*)d_in[0];
  const int*   ei   = (const int*)d_in[1];
  const float* W1   = (const float*)d_in[2];
  const float* att1 = (const float*)d_in[3];
  const float* b1   = (const float*)d_in[4];
  const float* W2   = (const float*)d_in[5];
  const float* att2 = (const float*)d_in[6];
  const float* b2   = (const float*)d_in[7];
  const float* W3   = (const float*)d_in[8];
  const float* att3 = (const float*)d_in[9];
  const float* b3   = (const float*)d_in[10];
  float* out = (float*)d_out;

  const int N  = in_sizes[0] / FDIM;   // 50000
  const int E  = in_sizes[1] / 2;      // 800000
  const int ET = E + N;
  const int NB = (N + BNODES - 1) >> BSHIFT;  // 391 buckets (<=512)

  char* ws = (char*)d_ws;
  auto carve = [&](size_t bytes) {
    char* p = ws; ws += (bytes + 15) & ~(size_t)15; return p;
  };
  __half*   xwh       = (__half*)carve((size_t)N * 64 * 2);  // fp16 rows
  float*    hfeat     = (float*)carve((size_t)N * 64 * 4);
  float*    pk3       = (float*)carve((size_t)N * 8 * 4);   // (xw3,aj3) pairs
  float*    ai3       = (float*)carve((size_t)N * 4 * 4);
  float*    ai        = (float*)carve((size_t)N * 8 * 4);
  float*    aj        = (float*)carve((size_t)N * 8 * 4);
  int*      rowstart  = (int*)carve((size_t)(N + 1) * 4);
  int*      colidx    = (int*)carve((size_t)ET * 4);
  int*      stflag    = (int*)carve(16);
  int*      bucketCnt = (int*)carve(512 * 4);
  int*      bucketBas = (int*)carve(513 * 4);
  int*      bucketFil = (int*)carve(512 * 4);
  size_t need = (size_t)(ws - (char*)d_ws);
  if (ws_size < need) return;
  // pairbuf aliases hfeat (12.8MB >= ET*4=3.4MB); CSR build completes before
  // layer-1 gather writes hfeat.
  unsigned* pairbuf = (unsigned*)hfeat;

  // ---- CSR build: bucketed counting sort (once; shared by all 3 layers) ----
  init_kernel<<<(NB + 255) / 256 + 1, 256, 0, stream>>>(ei, E, bucketCnt, NB, stflag);
  hist_kernel<<<128, 256, 0, stream>>>(ei, stflag, E, N, NB, bucketCnt);
  bucket_scan_kernel<<<1, 512, 0, stream>>>(bucketCnt, NB, bucketBas, bucketFil,
                                            rowstart, N, ET);
  binscatter_kernel<<<(ET + BINCH - 1) / BINCH, 256, 0, stream>>>(
      ei, stflag, E, N, NB, bucketFil, pairbuf, ET);
  bucketbuild_kernel<<<NB, 256, 0, stream>>>(pairbuf, bucketBas, N, ET,
                                             rowstart, colidx);

  const int nodeBlocks4 = (N + 3) / 4;
  const int laneBlocks4 = (N * 4 + 255) / 256;
  const int gemmTiles   = (N + 63) / 64;

  // ---- layer 1 ----
  gemm_att64_kernel<<<gemmTiles, 256, 0, stream>>>(X, W1, att1, N, xwh, ai, aj);
  gather64_kernel<<<nodeBlocks4, 256, 0, stream>>>(
      xwh, ai, aj, rowstart, colidx, b1, N, hfeat, 0, nullptr, nullptr,
      nullptr, nullptr);
  // ---- layer 2 (+ fused layer-3 projection) ----
  gemm_att64_kernel<<<gemmTiles, 256, 0, stream>>>(hfeat, W2, att2, N, xwh, ai, aj);
  gather64_kernel<<<nodeBlocks4, 256, 0, stream>>>(
      xwh, ai, aj, rowstart, colidx, b2, N, nullptr, 1, W3, att3, pk3, ai3);
  // ---- layer 3 aggregation ----
  gather4_kernel<<<laneBlocks4, 256, 0, stream>>>(pk3, ai3, rowstart, colidx,
                                                  b3, N, out);
}